// Round 20
// baseline (149.708 us; speedup 1.0000x reference)
//
#include <hip/hip_runtime.h>
#include <hip/hip_bf16.h>

#define NB 4
#define NS 2048
#define ND 768
#define NH 12
#define NDH 64
#define NM (NB * NS)  // 8192

// fold 1/sqrt(64) * log2(e) into Q so softmax = exp2(s); mask pre-scaled
#define QSCALE 0.1803368867f
#define MSCALE (-1.442695041e9f)

typedef __attribute__((ext_vector_type(8))) short short8;    // 8 x bf16
typedef __attribute__((ext_vector_type(4))) float f32x4;
typedef __attribute__((ext_vector_type(16))) float f32x16;

__device__ __forceinline__ void async_ld16(const void* g, void* l) {
  __builtin_amdgcn_global_load_lds(
      (const __attribute__((address_space(1))) void*)g,
      (__attribute__((address_space(3))) void*)l, 16, 0, 0);
}

// rounding pack (cold paths / epilogue)
__device__ __forceinline__ unsigned pack_bf16(float a, float b) {
  return ((unsigned)__bfloat16_as_ushort(__float2bfloat16(b)) << 16) |
         (unsigned)__bfloat16_as_ushort(__float2bfloat16(a));
}

// truncating pack: 1x v_perm_b32. D = {lo: bf16_trunc(a), hi: bf16_trunc(b)}
__device__ __forceinline__ unsigned pack_trunc(float a, float b) {
  return __builtin_amdgcn_perm(__float_as_uint(a), __float_as_uint(b),
                               0x03020706u);
}

// VALU cross-half exchange
__device__ __forceinline__ void permlane_swap(unsigned& a, unsigned& b) {
  asm("v_permlane32_swap_b32 %0, %1" : "+v"(a), "+v"(b));
}

// raw v_exp_f32: exp2 with flush-to-zero for large-negative (exact for mask)
__device__ __forceinline__ float fast_exp2(float x) {
  float r;
  asm("v_exp_f32 %0, %1" : "=v"(r) : "v"(x));
  return r;
}

// ------- fused prep: x->bf16 | W^T bf16 | mask crow-perm + bitmap ---------
// blocks [0,3072): convert; [3072,3648): transpose_w; [3648,3652): mask.
__global__ __launch_bounds__(256) void prep_kernel(
    const float* __restrict__ x, const float* __restrict__ mask,
    const float* __restrict__ w0, const float* __restrict__ w1,
    const float* __restrict__ w2, const float* __restrict__ w3,
    __hip_bfloat16* __restrict__ xb, float* __restrict__ mperm_g,
    unsigned* __restrict__ mbits, __hip_bfloat16* __restrict__ WtAll) {
  __shared__ __align__(16) char pshm[8448];
  const int bid = blockIdx.x;
  const int t = threadIdx.x;

  if (bid < 3072) {
    // ---- convert: 8 f32 -> 8 bf16 per thread, exact coverage ----
    const int i = bid * 256 + t;
    const float4 a = ((const float4*)x)[i * 2];
    const float4 b = ((const float4*)x)[i * 2 + 1];
    short8 v;
    __hip_bfloat16* p = (__hip_bfloat16*)&v;
    p[0] = __float2bfloat16(a.x); p[1] = __float2bfloat16(a.y);
    p[2] = __float2bfloat16(a.z); p[3] = __float2bfloat16(a.w);
    p[4] = __float2bfloat16(b.x); p[5] = __float2bfloat16(b.y);
    p[6] = __float2bfloat16(b.z); p[7] = __float2bfloat16(b.w);
    ((short8*)xb)[i] = v;
  } else if (bid < 3648) {
    // ---- weight transpose: W[K][N] f32 -> Wt[N][K] bf16 ----
    auto tile = (__hip_bfloat16(*)[66])pshm;
    const int tt = bid - 3072;           // 0..575 = 4 * 12 * 12
    const int bz = tt / 144;
    const int rem = tt % 144;
    const int kk0 = (rem / 12) * 64, nn0 = (rem % 12) * 64;
    const float* src = bz == 0 ? w0 : bz == 1 ? w1 : bz == 2 ? w2 : w3;
    __hip_bfloat16* dst = WtAll + (size_t)bz * ND * ND;
#pragma unroll
    for (int pp = 0; pp < 4; ++pp) {
      const int idx = pp * 256 + t;
      const int k = idx >> 4;
      const int c = (idx & 15) * 4;
      const float4 v = *(const float4*)(src + (size_t)(kk0 + k) * ND + nn0 + c);
      __hip_bfloat162* tp = (__hip_bfloat162*)&tile[k][c];
      tp[0] = __hip_bfloat162{__float2bfloat16(v.x), __float2bfloat16(v.y)};
      tp[1] = __hip_bfloat162{__float2bfloat16(v.z), __float2bfloat16(v.w)};
    }
    __syncthreads();
#pragma unroll
    for (int pp = 0; pp < 2; ++pp) {
      const int idx = pp * 256 + t;
      const int n = idx >> 3;
      const int kb = (idx & 7) * 8;
      short8 v;
      __hip_bfloat16* pv = (__hip_bfloat16*)&v;
#pragma unroll
      for (int j = 0; j < 8; ++j) pv[j] = tile[kb + j][n];
      *(short8*)(dst + (size_t)(nn0 + n) * ND + kk0 + kb) = v;
    }
  } else {
    // ---- mask: crow-permuted + scaled, per-(b,tile) nonzero bitmap ----
    unsigned* red = (unsigned*)pshm;
    const int b = bid - 3648;
    unsigned mymask = 0;
#pragma unroll
    for (int j = 0; j < 8; ++j) {
      const int sb = t * 8 + j;
      const int tile = sb >> 6, slot = sb & 63;
      const int g = slot >> 5, hh = (slot >> 4) & 1, r = slot & 15;
      const int key = tile * 64 + g * 32 + 4 * hh + (r & 3) + 8 * (r >> 2);
      const float v = mask[b * NS + key];
      mperm_g[b * 2048 + sb] = v * MSCALE;
      if (v != 0.f) mymask |= 1u << tile;
    }
    red[t] = mymask;
    __syncthreads();
    for (int s = 128; s > 0; s >>= 1) {
      if (t < s) red[t] |= red[t + s];
      __syncthreads();
    }
    if (t == 0) mbits[b] = red[0];
  }
}

// ------- fused QKV GEMM: 128x128 tile, BK=64, XCD-grouped blocks ----------
// 32 MFMA per barrier-drain (2x amortization). 128B LDS rows; source
// pre-swizzle (l&7)^(l>>3), read slot (c*4+lt)^(lk&7) -> min bank traffic.
__global__ __launch_bounds__(256) void qkv_gemm_kernel(
    const __hip_bfloat16* __restrict__ A,
    const __hip_bfloat16* __restrict__ Bt,
    const float* __restrict__ bq, const float* __restrict__ bk,
    const float* __restrict__ bv,
    __hip_bfloat16* __restrict__ Qw, __hip_bfloat16* __restrict__ Kw,
    __hip_bfloat16* __restrict__ Vt) {
  __shared__ __hip_bfloat16 As[128 * 64];  // [row][k] 16KB
  __shared__ __hip_bfloat16 Bs[128 * 64];  // [col][k] 16KB
  const int K = ND;
  const int tid = threadIdx.x;
  const int w = tid >> 6, l = tid & 63;
  const int lk = l & 15, lt = l >> 4;
  // bijective XCD grouping: 1152 blocks = 8 * 144
  const int p = blockIdx.x + 18 * blockIdx.y;
  const int swzb = (p & 7) * 144 + (p >> 3);
  const int m0 = (swzb / 18) * 128, n0 = (swzb % 18) * 128;
  const int wr = w >> 1, wc = w & 1;

  f32x4 acc[4][4] = {};

  const int arow = w * 32 + (l >> 3);   // +8,+16,+24 per extra issue
  const int acol = ((l & 7) ^ (l >> 3)) * 8;   // pre-swizzled source
  const __hip_bfloat16* aptr = A + (size_t)(m0 + arow) * K + acol;
  const __hip_bfloat16* bptr = Bt + (size_t)(n0 + arow) * K + acol;
  __hip_bfloat16* asb = As + w * 2048;
  __hip_bfloat16* bsb = Bs + w * 2048;

  for (int k0 = 0; k0 < K; k0 += 64) {
    __syncthreads();
    async_ld16(aptr + k0, asb);
    async_ld16(aptr + (size_t)8 * K + k0, asb + 512);
    async_ld16(aptr + (size_t)16 * K + k0, asb + 1024);
    async_ld16(aptr + (size_t)24 * K + k0, asb + 1536);
    async_ld16(bptr + k0, bsb);
    async_ld16(bptr + (size_t)8 * K + k0, bsb + 512);
    async_ld16(bptr + (size_t)16 * K + k0, bsb + 1024);
    async_ld16(bptr + (size_t)24 * K + k0, bsb + 1536);
    __syncthreads();

#pragma unroll
    for (int c = 0; c < 2; ++c) {
      const int slot = ((c * 4 + lt) ^ (lk & 7)) * 8;
      short8 af[4], bf[4];
#pragma unroll
      for (int m = 0; m < 4; ++m)
        af[m] = *(const short8*)(As + (wr * 64 + m * 16 + lk) * 64 + slot);
#pragma unroll
      for (int n = 0; n < 4; ++n)
        bf[n] = *(const short8*)(Bs + (wc * 64 + n * 16 + lk) * 64 + slot);
#pragma unroll
      for (int m = 0; m < 4; ++m)
#pragma unroll
        for (int n = 0; n < 4; ++n)
          acc[m][n] = __builtin_amdgcn_mfma_f32_16x16x32_bf16(
              af[m], bf[n], acc[m][n], 0, 0, 0);
    }
  }

  const int mi = n0 / ND;          // 0=Q, 1=K, 2=V (768/128=6: no straddle)
  const int nbase = n0 - mi * ND;
  const float* bp = mi == 0 ? bq : mi == 1 ? bk : bv;
  const float oscale = (mi == 0) ? QSCALE : 1.f;

#pragma unroll
  for (int n = 0; n < 4; ++n) {
    const int col = nbase + wc * 64 + n * 16 + lk;
    const float bb = bp[col];
#pragma unroll
    for (int m = 0; m < 4; ++m) {
      const int row = m0 + wr * 64 + m * 16 + lt * 4;
      if (mi < 2) {
#pragma unroll
        for (int r = 0; r < 4; ++r) {
          const float v = (acc[m][n][r] + bb) * oscale;
          (mi ? Kw : Qw)[(size_t)(row + r) * ND + col] = __float2bfloat16(v);
        }
      } else {
        // V^T: rows row..row+3 are consecutive s for fixed dh -> one uint2
        const int bidx = row >> 11, s = row & 2047;
        const int hh = col >> 6, dh = col & 63;
        const unsigned lo = pack_bf16(acc[m][n][0] + bb, acc[m][n][1] + bb);
        const unsigned hi2 = pack_bf16(acc[m][n][2] + bb, acc[m][n][3] + bb);
        *(uint2*)(Vt + (((size_t)bidx * NH + hh) * NDH + dh) * NS + s) =
            uint2{lo, hi2};
      }
    }
  }
}

// ---------------- MFMA-32x32 flash attention (R18 + setprio) --------------
// XCD-swizzled blocks, double-buffered LDS staging, vmcnt(0)+barrier per
// tile, t-loop unrolled x2 (compile-time buffer offsets, hoisted bases).
// P-pack = single v_perm_b32 truncation. s_setprio(1) around MFMA clusters
// (3 independent blocks/CU provide the wave role diversity T5 needs).
__global__ __launch_bounds__(256) void mha_mfma32_kernel(
    const __hip_bfloat16* __restrict__ Qb, const __hip_bfloat16* __restrict__ Kb,
    const __hip_bfloat16* __restrict__ Vt, const float* __restrict__ mperm_g,
    const unsigned* __restrict__ maskbits, __hip_bfloat16* __restrict__ ctx) {
  // [0,16384): K bufs (2x8KB) | [16384,32768): V bufs
  __shared__ __align__(16) char smem[32768];
  char* KsB = smem;
  char* VsB = smem + 16384;

  // bijective XCD swizzle: physical p -> logical (p&7)*96 + (p>>3)
  const int p = blockIdx.x + 16 * (blockIdx.y + 12 * blockIdx.z);
  const int logical = (p & 7) * 96 + (p >> 3);
  const int lx = logical & 15;         // q-tile
  const int rest = logical >> 4;       // 0..47
  const int h = rest % 12;
  const int b = rest / 12;

  const int tid = threadIdx.x;
  const int w = tid >> 6, l = tid & 63;
  const int l31 = l & 31, hi = l >> 5;
  const int q0 = lx * 128 + w * 32;
  const unsigned mbitsb = maskbits[b];   // wave-uniform

  const __hip_bfloat16* qp = Qb + ((size_t)b * NS + q0 + l31) * ND + h * NDH;
  short8 qf[4];
#pragma unroll
  for (int ks = 0; ks < 4; ++ks)
    qf[ks] = *(const short8*)(qp + ks * 16 + hi * 8);

  // all-ones bf16 A-fragment for the denominator MFMA
  const short ONEB = 0x3F80;
  const short8 ones = {ONEB, ONEB, ONEB, ONEB, ONEB, ONEB, ONEB, ONEB};

  f32x16 c0 = {}, c1 = {}, lacc = {};
  const f32x16 z16 = {};

  const int srow = l >> 3, slot = l & 7;
  const int key1 = w * 8 + srow, key2 = key1 + 32;
  const __hip_bfloat16* kg1 =
      Kb + ((size_t)b * NS + key1) * ND + h * NDH + (slot ^ (key1 & 7)) * 8;
  const __hip_bfloat16* kg2 =
      Kb + ((size_t)b * NS + key2) * ND + h * NDH + (slot ^ (key2 & 7)) * 8;
  const __hip_bfloat16* vg1 =
      Vt + (((size_t)b * NH + h) * NDH + key1) * NS + (slot ^ (key1 & 7)) * 8;
  const __hip_bfloat16* vg2 =
      Vt + (((size_t)b * NH + h) * NDH + key2) * NS + (slot ^ (key2 & 7)) * 8;
  const int ldsoff = w * 1024;
  const float* mg = mperm_g + (size_t)b * NS;  // crow-permuted, pre-scaled

  // uniform 4 async loads per wave per stage (vmcnt accounting)
#define STAGE(buf, t)                                                        \
  {                                                                          \
    const size_t koff = (size_t)(t) * 64 * ND;                               \
    char* kd = KsB + (buf) * 8192 + ldsoff;                                  \
    char* vd = VsB + (buf) * 8192 + ldsoff;                                  \
    async_ld16(kg1 + koff, kd);                                              \
    async_ld16(kg2 + koff, kd + 4096);                                       \
    async_ld16(vg1 + (t) * 64, vd);                                          \
    async_ld16(vg2 + (t) * 64, vd + 4096);                                   \
  }

  const int swz = (l31 & 7) << 4;

  // 4 hoisted per-lane base pointers; every LDS read in the loop is
  // base + immediate (K row2 +4096, V +16384, V row2 +20480, buf +8192).
  const char* pks[4];
#pragma unroll
  for (int ks = 0; ks < 4; ++ks)
    pks[ks] = KsB + (l31 << 7) + (((ks << 5) | (hi << 4)) ^ swz);

  auto compute_tile = [&](int t, int bufo) {
    // ---- QK^T, C starts from persistent zero regs ----
    f32x16 s0, s1;
    __builtin_amdgcn_s_setprio(1);
#pragma unroll
    for (int ks = 0; ks < 4; ++ks) {
      const short8 kf0 = *(const short8*)(pks[ks] + bufo);
      const short8 kf1 = *(const short8*)(pks[ks] + bufo + 4096);
      if (ks == 0) {
        s0 = __builtin_amdgcn_mfma_f32_32x32x16_bf16(kf0, qf[0], z16, 0, 0, 0);
        s1 = __builtin_amdgcn_mfma_f32_32x32x16_bf16(kf1, qf[0], z16, 0, 0, 0);
      } else {
        s0 = __builtin_amdgcn_mfma_f32_32x32x16_bf16(kf0, qf[ks], s0, 0, 0, 0);
        s1 = __builtin_amdgcn_mfma_f32_32x32x16_bf16(kf1, qf[ks], s1, 0, 0, 0);
      }
    }
    __builtin_amdgcn_s_setprio(0);

    // ---- rare path: this tile has nonzero mask values (additive) ----
    if ((mbitsb >> t) & 1) {
      const float* mgt = mg + t * 64 + hi * 16;
#pragma unroll
      for (int r = 0; r < 16; ++r) {
        s0[r] += mgt[r];
        s1[r] += mgt[32 + r];
      }
    }

    // ---- softmax: p = exp2(s), raw v_exp_f32 (sum deferred to MFMA) ----
#pragma unroll
    for (int r = 0; r < 16; ++r) s0[r] = fast_exp2(s0[r]);
#pragma unroll
    for (int r = 0; r < 16; ++r) s1[r] = fast_exp2(s1[r]);

    // ---- PV: P^T B-frags via v_perm truncation + permlane32_swap;
    //      denominator via ones-MFMA (same truncated P -> bias cancels) ----
    __builtin_amdgcn_s_setprio(1);
#pragma unroll
    for (int ks = 0; ks < 4; ++ks) {
      const f32x16& S = (ks < 2) ? s0 : s1;
      const int r0 = (ks & 1) * 8;
      unsigned u0 = pack_trunc(S[r0 + 0], S[r0 + 1]);
      unsigned u1 = pack_trunc(S[r0 + 2], S[r0 + 3]);
      unsigned u2 = pack_trunc(S[r0 + 4], S[r0 + 5]);
      unsigned u3 = pack_trunc(S[r0 + 6], S[r0 + 7]);
      permlane_swap(u0, u2);
      permlane_swap(u1, u3);
      union { unsigned u[4]; short8 v; } pf = {{u0, u1, u2, u3}};
      const short8 vf0 = *(const short8*)(pks[ks] + bufo + 16384);
      c0 = __builtin_amdgcn_mfma_f32_32x32x16_bf16(vf0, pf.v, c0, 0, 0, 0);
      const short8 vf1 = *(const short8*)(pks[ks] + bufo + 20480);
      c1 = __builtin_amdgcn_mfma_f32_32x32x16_bf16(vf1, pf.v, c1, 0, 0, 0);
      lacc = __builtin_amdgcn_mfma_f32_32x32x16_bf16(ones, pf.v, lacc, 0, 0, 0);
    }
    __builtin_amdgcn_s_setprio(0);
  };

  STAGE(0, 0);
#pragma unroll 1
  for (int t = 0; t < 32; t += 2) {
    // tile t's 4 loads done; all waves synced -> buf 1 free to restage
    asm volatile("s_waitcnt vmcnt(0)" ::: "memory");
    __builtin_amdgcn_s_barrier();
    STAGE(1, t + 1);
    compute_tile(t, 0);
    asm volatile("s_waitcnt vmcnt(0)" ::: "memory");
    __builtin_amdgcn_s_barrier();
    if (t + 2 < 32) STAGE(0, t + 2);
    compute_tile(t + 1, 8192);
  }

  // every row of lacc holds this lane's q-row denominator
  const float inv = 1.f / lacc[0];

  // ---- epilogue: LDS bounce [32][76] -> 16B stores (rounding packs) ----
  __syncthreads();
  __hip_bfloat16* cb = (__hip_bfloat16*)(smem + w * 4864);  // 32*76*2 B
#pragma unroll
  for (int mg2 = 0; mg2 < 2; ++mg2) {
    const f32x16& cc = mg2 ? c1 : c0;
#pragma unroll
    for (int rr = 0; rr < 4; ++rr) {
      const unsigned u0 = pack_bf16(cc[rr * 4 + 0] * inv, cc[rr * 4 + 1] * inv);
      const unsigned u1 = pack_bf16(cc[rr * 4 + 2] * inv, cc[rr * 4 + 3] * inv);
      *(uint2*)(cb + l31 * 76 + mg2 * 32 + 4 * hi + 8 * rr) = uint2{u0, u1};
    }
  }
  __syncthreads();
  const __hip_bfloat16* crd =
      (const __hip_bfloat16*)(smem + w * 4864) + (l >> 1) * 76 + (l & 1) * 8;
  __hip_bfloat16* gout =
      ctx + ((size_t)b * NS + q0 + (l >> 1)) * ND + h * NDH + (l & 1) * 8;
#pragma unroll
  for (int i = 0; i < 4; ++i) {
    const uint2 a = *(const uint2*)(crd + i * 16);
    const uint2 b2 = *(const uint2*)(crd + i * 16 + 4);
    *(uint4*)(gout + i * 16) = uint4{a.x, a.y, b2.x, b2.y};
  }
#undef STAGE
}

// ---------------- MFMA GEMM (output proj): 128x64, BK=64, f32 out ---------
__global__ __launch_bounds__(256) void gemm_bt_mfma_kernel(
    const __hip_bfloat16* __restrict__ A, const __hip_bfloat16* __restrict__ Bt,
    const float* __restrict__ bias, float* __restrict__ Cout,
    int M, int N, int K) {
  __shared__ __hip_bfloat16 As[128 * 64];  // 16KB
  __shared__ __hip_bfloat16 Bs[64 * 64];   // 8KB
  const int tid = threadIdx.x;
  const int w = tid >> 6, l = tid & 63;
  const int lk = l & 15, lt = l >> 4;
  // bijective XCD grouping: 768 blocks = 8 * 96
  const int p = blockIdx.x + 12 * blockIdx.y;
  const int swzb = (p & 7) * 96 + (p >> 3);
  const int m0 = (swzb / 12) * 128, n0 = (swzb % 12) * 64;
  const int wr = w >> 1, wc = w & 1;

  f32x4 acc[4][2] = {};

  const int arow = w * 32 + (l >> 3);
  const int acol = ((l & 7) ^ (l >> 3)) * 8;   // pre-swizzled source
  const __hip_bfloat16* aptr = A + (size_t)(m0 + arow) * K + acol;
  const int brow = w * 16 + (l >> 3);
  const __hip_bfloat16* bptr = Bt + (size_t)(n0 + brow) * K + acol;
  __hip_bfloat16* asb = As + w * 2048;
  __hip_bfloat16* bsb = Bs + w * 1024;

  for (int k0 = 0; k0 < K; k0 += 64) {
    __syncthreads();
    async_ld16(aptr + k0, asb);
    async_ld16(aptr + (size_t)8 * K + k0, asb + 512);
    async_ld16(aptr + (size_t)16 * K + k0, asb + 1024);
    async_ld16(aptr + (size_t)24 * K + k0, asb + 1536);
    async_ld16(bptr + k0, bsb);
    async_ld16(bptr + (size_t)8 * K + k0, bsb + 512);
    __syncthreads();

#pragma unroll
    for (int c = 0; c < 2; ++c) {
      const int slot = ((c * 4 + lt) ^ (lk & 7)) * 8;
      short8 af[4], bf[2];
#pragma unroll
      for (int m = 0; m < 4; ++m)
        af[m] = *(const short8*)(As + (wr * 64 + m * 16 + lk) * 64 + slot);
#pragma unroll
      for (int n = 0; n < 2; ++n)
        bf[n] = *(const short8*)(Bs + (wc * 32 + n * 16 + lk) * 64 + slot);
#pragma unroll
      for (int m = 0; m < 4; ++m)
#pragma unroll
        for (int n = 0; n < 2; ++n)
          acc[m][n] = __builtin_amdgcn_mfma_f32_16x16x32_bf16(
              af[m], bf[n], acc[m][n], 0, 0, 0);
    }
  }

#pragma unroll
  for (int n = 0; n < 2; ++n) {
    const int col = n0 + wc * 32 + n * 16 + lk;
    const float bb = bias[col];
#pragma unroll
    for (int m = 0; m < 4; ++m) {
      const int row = m0 + wr * 64 + m * 16 + lt * 4;
#pragma unroll
      for (int r = 0; r < 4; ++r)
        Cout[(size_t)(row + r) * N + col] = acc[m][n][r] + bb;
    }
  }
}

extern "C" void kernel_launch(void* const* d_in, const int* in_sizes, int n_in,
                              void* d_out, int out_size, void* d_ws, size_t ws_size,
                              hipStream_t stream) {
  const float* x    = (const float*)d_in[0];
  const float* mask = (const float*)d_in[1];
  const float* wq   = (const float*)d_in[2];
  const float* bq   = (const float*)d_in[3];
  const float* wk   = (const float*)d_in[4];
  const float* bk   = (const float*)d_in[5];
  const float* wv   = (const float*)d_in[6];
  const float* bv   = (const float*)d_in[7];
  const float* wo   = (const float*)d_in[8];
  const float* bo   = (const float*)d_in[9];
  float* out = (float*)d_out;

  const size_t mat = (size_t)NM * ND;
  const size_t wmat = (size_t)ND * ND;
  __hip_bfloat16* xb    = (__hip_bfloat16*)d_ws;
  __hip_bfloat16* WtAll = xb + mat;
  __hip_bfloat16* Qw    = WtAll + 4 * wmat;
  __hip_bfloat16* Kw    = Qw + mat;
  __hip_bfloat16* Vtw   = Kw + mat;
  __hip_bfloat16* Cw    = Vtw + mat;
  float* mpg            = (float*)(Cw + mat);   // 8192 floats
  unsigned* mbits       = (unsigned*)(mpg + NM);  // 4 uints

  // fused prep: convert (3072) + transpose_w (576) + mask (4) = 3652 blocks
  prep_kernel<<<3652, 256, 0, stream>>>(x, mask, wq, wk, wv, wo,
                                        xb, mpg, mbits, WtAll);

  qkv_gemm_kernel<<<dim3(3 * ND / 128, NM / 128), 256, 0, stream>>>(
      xb, WtAll, bq, bk, bv, Qw, Kw, Vtw);

  mha_mfma32_kernel<<<dim3(NS / 128, NH, NB), 256, 0, stream>>>(
      Qw, Kw, Vtw, mpg, mbits, Cw);

  gemm_bt_mfma_kernel<<<dim3(ND / 64, NM / 128), 256, 0, stream>>>(
      Cw, WtAll + 3 * wmat, bo, out, NM, ND, ND);
}

// Round 21
// 144.489 us; speedup vs baseline: 1.0361x; 1.0361x over previous
//
#include <hip/hip_runtime.h>
#include <hip/hip_bf16.h>

#define NB 4
#define NS 2048
#define ND 768
#define NH 12
#define NDH 64
#define NM (NB * NS)  // 8192

// fold 1/sqrt(64) * log2(e) into Q so softmax = exp2(s); mask pre-scaled
#define QSCALE 0.1803368867f
#define MSCALE (-1.442695041e9f)

typedef __attribute__((ext_vector_type(8))) short short8;    // 8 x bf16
typedef __attribute__((ext_vector_type(4))) float f32x4;
typedef __attribute__((ext_vector_type(16))) float f32x16;

__device__ __forceinline__ void async_ld16(const void* g, void* l) {
  __builtin_amdgcn_global_load_lds(
      (const __attribute__((address_space(1))) void*)g,
      (__attribute__((address_space(3))) void*)l, 16, 0, 0);
}

// rounding pack (cold paths / epilogue)
__device__ __forceinline__ unsigned pack_bf16(float a, float b) {
  return ((unsigned)__bfloat16_as_ushort(__float2bfloat16(b)) << 16) |
         (unsigned)__bfloat16_as_ushort(__float2bfloat16(a));
}

// truncating pack: 1x v_perm_b32. D = {lo: bf16_trunc(a), hi: bf16_trunc(b)}
__device__ __forceinline__ unsigned pack_trunc(float a, float b) {
  return __builtin_amdgcn_perm(__float_as_uint(a), __float_as_uint(b),
                               0x03020706u);
}

// VALU cross-half exchange
__device__ __forceinline__ void permlane_swap(unsigned& a, unsigned& b) {
  asm("v_permlane32_swap_b32 %0, %1" : "+v"(a), "+v"(b));
}

// raw v_exp_f32: exp2 with flush-to-zero for large-negative (exact for mask)
__device__ __forceinline__ float fast_exp2(float x) {
  float r;
  asm("v_exp_f32 %0, %1" : "=v"(r) : "v"(x));
  return r;
}

// ------- fused prep: x->bf16 | W^T bf16 | mask crow-perm + bitmap ---------
// blocks [0,3072): convert; [3072,3648): transpose_w; [3648,3652): mask.
__global__ __launch_bounds__(256) void prep_kernel(
    const float* __restrict__ x, const float* __restrict__ mask,
    const float* __restrict__ w0, const float* __restrict__ w1,
    const float* __restrict__ w2, const float* __restrict__ w3,
    __hip_bfloat16* __restrict__ xb, float* __restrict__ mperm_g,
    unsigned* __restrict__ mbits, __hip_bfloat16* __restrict__ WtAll) {
  __shared__ __align__(16) char pshm[8448];
  const int bid = blockIdx.x;
  const int t = threadIdx.x;

  if (bid < 3072) {
    // ---- convert: 8 f32 -> 8 bf16 per thread, exact coverage ----
    const int i = bid * 256 + t;
    const float4 a = ((const float4*)x)[i * 2];
    const float4 b = ((const float4*)x)[i * 2 + 1];
    short8 v;
    __hip_bfloat16* p = (__hip_bfloat16*)&v;
    p[0] = __float2bfloat16(a.x); p[1] = __float2bfloat16(a.y);
    p[2] = __float2bfloat16(a.z); p[3] = __float2bfloat16(a.w);
    p[4] = __float2bfloat16(b.x); p[5] = __float2bfloat16(b.y);
    p[6] = __float2bfloat16(b.z); p[7] = __float2bfloat16(b.w);
    ((short8*)xb)[i] = v;
  } else if (bid < 3648) {
    // ---- weight transpose: W[K][N] f32 -> Wt[N][K] bf16 ----
    auto tile = (__hip_bfloat16(*)[66])pshm;
    const int tt = bid - 3072;           // 0..575 = 4 * 12 * 12
    const int bz = tt / 144;
    const int rem = tt % 144;
    const int kk0 = (rem / 12) * 64, nn0 = (rem % 12) * 64;
    const float* src = bz == 0 ? w0 : bz == 1 ? w1 : bz == 2 ? w2 : w3;
    __hip_bfloat16* dst = WtAll + (size_t)bz * ND * ND;
#pragma unroll
    for (int pp = 0; pp < 4; ++pp) {
      const int idx = pp * 256 + t;
      const int k = idx >> 4;
      const int c = (idx & 15) * 4;
      const float4 v = *(const float4*)(src + (size_t)(kk0 + k) * ND + nn0 + c);
      __hip_bfloat162* tp = (__hip_bfloat162*)&tile[k][c];
      tp[0] = __hip_bfloat162{__float2bfloat16(v.x), __float2bfloat16(v.y)};
      tp[1] = __hip_bfloat162{__float2bfloat16(v.z), __float2bfloat16(v.w)};
    }
    __syncthreads();
#pragma unroll
    for (int pp = 0; pp < 2; ++pp) {
      const int idx = pp * 256 + t;
      const int n = idx >> 3;
      const int kb = (idx & 7) * 8;
      short8 v;
      __hip_bfloat16* pv = (__hip_bfloat16*)&v;
#pragma unroll
      for (int j = 0; j < 8; ++j) pv[j] = tile[kb + j][n];
      *(short8*)(dst + (size_t)(nn0 + n) * ND + kk0 + kb) = v;
    }
  } else {
    // ---- mask: crow-permuted + scaled, per-(b,tile) nonzero bitmap ----
    unsigned* red = (unsigned*)pshm;
    const int b = bid - 3648;
    unsigned mymask = 0;
#pragma unroll
    for (int j = 0; j < 8; ++j) {
      const int sb = t * 8 + j;
      const int tile = sb >> 6, slot = sb & 63;
      const int g = slot >> 5, hh = (slot >> 4) & 1, r = slot & 15;
      const int key = tile * 64 + g * 32 + 4 * hh + (r & 3) + 8 * (r >> 2);
      const float v = mask[b * NS + key];
      mperm_g[b * 2048 + sb] = v * MSCALE;
      if (v != 0.f) mymask |= 1u << tile;
    }
    red[t] = mymask;
    __syncthreads();
    for (int s = 128; s > 0; s >>= 1) {
      if (t < s) red[t] |= red[t + s];
      __syncthreads();
    }
    if (t == 0) mbits[b] = red[0];
  }
}

// ------- fused QKV GEMM: 128x128 tile, BK=64, XCD-grouped blocks ----------
// 32 MFMA per barrier-drain (2x amortization). 128B LDS rows; source
// pre-swizzle (l&7)^(l>>3), read slot (c*4+lt)^(lk&7) -> min bank traffic.
__global__ __launch_bounds__(256) void qkv_gemm_kernel(
    const __hip_bfloat16* __restrict__ A,
    const __hip_bfloat16* __restrict__ Bt,
    const float* __restrict__ bq, const float* __restrict__ bk,
    const float* __restrict__ bv,
    __hip_bfloat16* __restrict__ Qw, __hip_bfloat16* __restrict__ Kw,
    __hip_bfloat16* __restrict__ Vt) {
  __shared__ __hip_bfloat16 As[128 * 64];  // [row][k] 16KB
  __shared__ __hip_bfloat16 Bs[128 * 64];  // [col][k] 16KB
  const int K = ND;
  const int tid = threadIdx.x;
  const int w = tid >> 6, l = tid & 63;
  const int lk = l & 15, lt = l >> 4;
  // bijective XCD grouping: 1152 blocks = 8 * 144
  const int p = blockIdx.x + 18 * blockIdx.y;
  const int swzb = (p & 7) * 144 + (p >> 3);
  const int m0 = (swzb / 18) * 128, n0 = (swzb % 18) * 128;
  const int wr = w >> 1, wc = w & 1;

  f32x4 acc[4][4] = {};

  const int arow = w * 32 + (l >> 3);   // +8,+16,+24 per extra issue
  const int acol = ((l & 7) ^ (l >> 3)) * 8;   // pre-swizzled source
  const __hip_bfloat16* aptr = A + (size_t)(m0 + arow) * K + acol;
  const __hip_bfloat16* bptr = Bt + (size_t)(n0 + arow) * K + acol;
  __hip_bfloat16* asb = As + w * 2048;
  __hip_bfloat16* bsb = Bs + w * 2048;

  for (int k0 = 0; k0 < K; k0 += 64) {
    __syncthreads();
    async_ld16(aptr + k0, asb);
    async_ld16(aptr + (size_t)8 * K + k0, asb + 512);
    async_ld16(aptr + (size_t)16 * K + k0, asb + 1024);
    async_ld16(aptr + (size_t)24 * K + k0, asb + 1536);
    async_ld16(bptr + k0, bsb);
    async_ld16(bptr + (size_t)8 * K + k0, bsb + 512);
    async_ld16(bptr + (size_t)16 * K + k0, bsb + 1024);
    async_ld16(bptr + (size_t)24 * K + k0, bsb + 1536);
    __syncthreads();

#pragma unroll
    for (int c = 0; c < 2; ++c) {
      const int slot = ((c * 4 + lt) ^ (lk & 7)) * 8;
      short8 af[4], bf[4];
#pragma unroll
      for (int m = 0; m < 4; ++m)
        af[m] = *(const short8*)(As + (wr * 64 + m * 16 + lk) * 64 + slot);
#pragma unroll
      for (int n = 0; n < 4; ++n)
        bf[n] = *(const short8*)(Bs + (wc * 64 + n * 16 + lk) * 64 + slot);
#pragma unroll
      for (int m = 0; m < 4; ++m)
#pragma unroll
        for (int n = 0; n < 4; ++n)
          acc[m][n] = __builtin_amdgcn_mfma_f32_16x16x32_bf16(
              af[m], bf[n], acc[m][n], 0, 0, 0);
    }
  }

  const int mi = n0 / ND;          // 0=Q, 1=K, 2=V (768/128=6: no straddle)
  const int nbase = n0 - mi * ND;
  const float* bp = mi == 0 ? bq : mi == 1 ? bk : bv;
  const float oscale = (mi == 0) ? QSCALE : 1.f;

#pragma unroll
  for (int n = 0; n < 4; ++n) {
    const int col = nbase + wc * 64 + n * 16 + lk;
    const float bb = bp[col];
#pragma unroll
    for (int m = 0; m < 4; ++m) {
      const int row = m0 + wr * 64 + m * 16 + lt * 4;
      if (mi < 2) {
#pragma unroll
        for (int r = 0; r < 4; ++r) {
          const float v = (acc[m][n][r] + bb) * oscale;
          (mi ? Kw : Qw)[(size_t)(row + r) * ND + col] = __float2bfloat16(v);
        }
      } else {
        // V^T: rows row..row+3 are consecutive s for fixed dh -> one uint2
        const int bidx = row >> 11, s = row & 2047;
        const int hh = col >> 6, dh = col & 63;
        const unsigned lo = pack_bf16(acc[m][n][0] + bb, acc[m][n][1] + bb);
        const unsigned hi2 = pack_bf16(acc[m][n][2] + bb, acc[m][n][3] + bb);
        *(uint2*)(Vt + (((size_t)bidx * NH + hh) * NDH + dh) * NS + s) =
            uint2{lo, hi2};
      }
    }
  }
}

// ---------------- MFMA-32x32 flash attention (R18 structure) --------------
// XCD-swizzled blocks, double-buffered LDS staging, vmcnt(0)+barrier per
// tile, t-loop unrolled x2 (compile-time buffer offsets, hoisted bases).
// P-pack = single v_perm_b32 truncation (bias cancels in softmax ratio).
__global__ __launch_bounds__(256) void mha_mfma32_kernel(
    const __hip_bfloat16* __restrict__ Qb, const __hip_bfloat16* __restrict__ Kb,
    const __hip_bfloat16* __restrict__ Vt, const float* __restrict__ mperm_g,
    const unsigned* __restrict__ maskbits, __hip_bfloat16* __restrict__ ctx) {
  // [0,16384): K bufs (2x8KB) | [16384,32768): V bufs
  __shared__ __align__(16) char smem[32768];
  char* KsB = smem;
  char* VsB = smem + 16384;

  // bijective XCD swizzle: physical p -> logical (p&7)*96 + (p>>3)
  const int p = blockIdx.x + 16 * (blockIdx.y + 12 * blockIdx.z);
  const int logical = (p & 7) * 96 + (p >> 3);
  const int lx = logical & 15;         // q-tile
  const int rest = logical >> 4;       // 0..47
  const int h = rest % 12;
  const int b = rest / 12;

  const int tid = threadIdx.x;
  const int w = tid >> 6, l = tid & 63;
  const int l31 = l & 31, hi = l >> 5;
  const int q0 = lx * 128 + w * 32;
  const unsigned mbitsb = maskbits[b];   // wave-uniform

  const __hip_bfloat16* qp = Qb + ((size_t)b * NS + q0 + l31) * ND + h * NDH;
  short8 qf[4];
#pragma unroll
  for (int ks = 0; ks < 4; ++ks)
    qf[ks] = *(const short8*)(qp + ks * 16 + hi * 8);

  // all-ones bf16 A-fragment for the denominator MFMA
  const short ONEB = 0x3F80;
  const short8 ones = {ONEB, ONEB, ONEB, ONEB, ONEB, ONEB, ONEB, ONEB};

  f32x16 c0 = {}, c1 = {}, lacc = {};
  const f32x16 z16 = {};

  const int srow = l >> 3, slot = l & 7;
  const int key1 = w * 8 + srow, key2 = key1 + 32;
  const __hip_bfloat16* kg1 =
      Kb + ((size_t)b * NS + key1) * ND + h * NDH + (slot ^ (key1 & 7)) * 8;
  const __hip_bfloat16* kg2 =
      Kb + ((size_t)b * NS + key2) * ND + h * NDH + (slot ^ (key2 & 7)) * 8;
  const __hip_bfloat16* vg1 =
      Vt + (((size_t)b * NH + h) * NDH + key1) * NS + (slot ^ (key1 & 7)) * 8;
  const __hip_bfloat16* vg2 =
      Vt + (((size_t)b * NH + h) * NDH + key2) * NS + (slot ^ (key2 & 7)) * 8;
  const int ldsoff = w * 1024;
  const float* mg = mperm_g + (size_t)b * NS;  // crow-permuted, pre-scaled

  // uniform 4 async loads per wave per stage (vmcnt accounting)
#define STAGE(buf, t)                                                        \
  {                                                                          \
    const size_t koff = (size_t)(t) * 64 * ND;                               \
    char* kd = KsB + (buf) * 8192 + ldsoff;                                  \
    char* vd = VsB + (buf) * 8192 + ldsoff;                                  \
    async_ld16(kg1 + koff, kd);                                              \
    async_ld16(kg2 + koff, kd + 4096);                                       \
    async_ld16(vg1 + (t) * 64, vd);                                          \
    async_ld16(vg2 + (t) * 64, vd + 4096);                                   \
  }

  const int swz = (l31 & 7) << 4;

  // 4 hoisted per-lane base pointers; every LDS read in the loop is
  // base + immediate (K row2 +4096, V +16384, V row2 +20480, buf +8192).
  const char* pks[4];
#pragma unroll
  for (int ks = 0; ks < 4; ++ks)
    pks[ks] = KsB + (l31 << 7) + (((ks << 5) | (hi << 4)) ^ swz);

  auto compute_tile = [&](int t, int bufo) {
    // ---- QK^T, C starts from persistent zero regs ----
    f32x16 s0, s1;
#pragma unroll
    for (int ks = 0; ks < 4; ++ks) {
      const short8 kf0 = *(const short8*)(pks[ks] + bufo);
      const short8 kf1 = *(const short8*)(pks[ks] + bufo + 4096);
      if (ks == 0) {
        s0 = __builtin_amdgcn_mfma_f32_32x32x16_bf16(kf0, qf[0], z16, 0, 0, 0);
        s1 = __builtin_amdgcn_mfma_f32_32x32x16_bf16(kf1, qf[0], z16, 0, 0, 0);
      } else {
        s0 = __builtin_amdgcn_mfma_f32_32x32x16_bf16(kf0, qf[ks], s0, 0, 0, 0);
        s1 = __builtin_amdgcn_mfma_f32_32x32x16_bf16(kf1, qf[ks], s1, 0, 0, 0);
      }
    }

    // ---- rare path: this tile has nonzero mask values (additive) ----
    if ((mbitsb >> t) & 1) {
      const float* mgt = mg + t * 64 + hi * 16;
#pragma unroll
      for (int r = 0; r < 16; ++r) {
        s0[r] += mgt[r];
        s1[r] += mgt[32 + r];
      }
    }

    // ---- softmax: p = exp2(s), raw v_exp_f32 (sum deferred to MFMA) ----
#pragma unroll
    for (int r = 0; r < 16; ++r) s0[r] = fast_exp2(s0[r]);
#pragma unroll
    for (int r = 0; r < 16; ++r) s1[r] = fast_exp2(s1[r]);

    // ---- PV: P^T B-frags via v_perm truncation + permlane32_swap;
    //      denominator via ones-MFMA (same truncated P -> bias cancels) ----
#pragma unroll
    for (int ks = 0; ks < 4; ++ks) {
      const f32x16& S = (ks < 2) ? s0 : s1;
      const int r0 = (ks & 1) * 8;
      unsigned u0 = pack_trunc(S[r0 + 0], S[r0 + 1]);
      unsigned u1 = pack_trunc(S[r0 + 2], S[r0 + 3]);
      unsigned u2 = pack_trunc(S[r0 + 4], S[r0 + 5]);
      unsigned u3 = pack_trunc(S[r0 + 6], S[r0 + 7]);
      permlane_swap(u0, u2);
      permlane_swap(u1, u3);
      union { unsigned u[4]; short8 v; } pf = {{u0, u1, u2, u3}};
      const short8 vf0 = *(const short8*)(pks[ks] + bufo + 16384);
      c0 = __builtin_amdgcn_mfma_f32_32x32x16_bf16(vf0, pf.v, c0, 0, 0, 0);
      const short8 vf1 = *(const short8*)(pks[ks] + bufo + 20480);
      c1 = __builtin_amdgcn_mfma_f32_32x32x16_bf16(vf1, pf.v, c1, 0, 0, 0);
      lacc = __builtin_amdgcn_mfma_f32_32x32x16_bf16(ones, pf.v, lacc, 0, 0, 0);
    }
  };

  STAGE(0, 0);
#pragma unroll 1
  for (int t = 0; t < 32; t += 2) {
    // tile t's 4 loads done; all waves synced -> buf 1 free to restage
    asm volatile("s_waitcnt vmcnt(0) lgkmcnt(0)" ::: "memory");
    __builtin_amdgcn_s_barrier();
    STAGE(1, t + 1);
    compute_tile(t, 0);
    asm volatile("s_waitcnt vmcnt(0) lgkmcnt(0)" ::: "memory");
    __builtin_amdgcn_s_barrier();
    if (t + 2 < 32) STAGE(0, t + 2);
    compute_tile(t + 1, 8192);
  }

  // every row of lacc holds this lane's q-row denominator
  const float inv = 1.f / lacc[0];

  // ---- epilogue: LDS bounce [32][76] -> 16B stores (rounding packs) ----
  __syncthreads();
  __hip_bfloat16* cb = (__hip_bfloat16*)(smem + w * 4864);  // 32*76*2 B
#pragma unroll
  for (int mg2 = 0; mg2 < 2; ++mg2) {
    const f32x16& cc = mg2 ? c1 : c0;
#pragma unroll
    for (int rr = 0; rr < 4; ++rr) {
      const unsigned u0 = pack_bf16(cc[rr * 4 + 0] * inv, cc[rr * 4 + 1] * inv);
      const unsigned u1 = pack_bf16(cc[rr * 4 + 2] * inv, cc[rr * 4 + 3] * inv);
      *(uint2*)(cb + l31 * 76 + mg2 * 32 + 4 * hi + 8 * rr) = uint2{u0, u1};
    }
  }
  __syncthreads();
  const __hip_bfloat16* crd =
      (const __hip_bfloat16*)(smem + w * 4864) + (l >> 1) * 76 + (l & 1) * 8;
  __hip_bfloat16* gout =
      ctx + ((size_t)b * NS + q0 + (l >> 1)) * ND + h * NDH + (l & 1) * 8;
#pragma unroll
  for (int i = 0; i < 4; ++i) {
    const uint2 a = *(const uint2*)(crd + i * 16);
    const uint2 b2 = *(const uint2*)(crd + i * 16 + 4);
    *(uint4*)(gout + i * 16) = uint4{a.x, a.y, b2.x, b2.y};
  }
#undef STAGE
}

// ---------------- MFMA GEMM (output proj): 128x64, BK=64, f32 out ---------
__global__ __launch_bounds__(256) void gemm_bt_mfma_kernel(
    const __hip_bfloat16* __restrict__ A, const __hip_bfloat16* __restrict__ Bt,
    const float* __restrict__ bias, float* __restrict__ Cout,
    int M, int N, int K) {
  __shared__ __hip_bfloat16 As[128 * 64];  // 16KB
  __shared__ __hip_bfloat16 Bs[64 * 64];   // 8KB
  const int tid = threadIdx.x;
  const int w = tid >> 6, l = tid & 63;
  const int lk = l & 15, lt = l >> 4;
  // bijective XCD grouping: 768 blocks = 8 * 96
  const int p = blockIdx.x + 12 * blockIdx.y;
  const int swzb = (p & 7) * 96 + (p >> 3);
  const int m0 = (swzb / 12) * 128, n0 = (swzb % 12) * 64;
  const int wr = w >> 1, wc = w & 1;

  f32x4 acc[4][2] = {};

  const int arow = w * 32 + (l >> 3);
  const int acol = ((l & 7) ^ (l >> 3)) * 8;   // pre-swizzled source
  const __hip_bfloat16* aptr = A + (size_t)(m0 + arow) * K + acol;
  const int brow = w * 16 + (l >> 3);
  const __hip_bfloat16* bptr = Bt + (size_t)(n0 + brow) * K + acol;
  __hip_bfloat16* asb = As + w * 2048;
  __hip_bfloat16* bsb = Bs + w * 1024;

  for (int k0 = 0; k0 < K; k0 += 64) {
    __syncthreads();
    async_ld16(aptr + k0, asb);
    async_ld16(aptr + (size_t)8 * K + k0, asb + 512);
    async_ld16(aptr + (size_t)16 * K + k0, asb + 1024);
    async_ld16(aptr + (size_t)24 * K + k0, asb + 1536);
    async_ld16(bptr + k0, bsb);
    async_ld16(bptr + (size_t)8 * K + k0, bsb + 512);
    __syncthreads();

#pragma unroll
    for (int c = 0; c < 2; ++c) {
      const int slot = ((c * 4 + lt) ^ (lk & 7)) * 8;
      short8 af[4], bf[2];
#pragma unroll
      for (int m = 0; m < 4; ++m)
        af[m] = *(const short8*)(As + (wr * 64 + m * 16 + lk) * 64 + slot);
#pragma unroll
      for (int n = 0; n < 2; ++n)
        bf[n] = *(const short8*)(Bs + (wc * 32 + n * 16 + lk) * 64 + slot);
#pragma unroll
      for (int m = 0; m < 4; ++m)
#pragma unroll
        for (int n = 0; n < 2; ++n)
          acc[m][n] = __builtin_amdgcn_mfma_f32_16x16x32_bf16(
              af[m], bf[n], acc[m][n], 0, 0, 0);
    }
  }

#pragma unroll
  for (int n = 0; n < 2; ++n) {
    const int col = n0 + wc * 32 + n * 16 + lk;
    const float bb = bias[col];
#pragma unroll
    for (int m = 0; m < 4; ++m) {
      const int row = m0 + wr * 64 + m * 16 + lt * 4;
#pragma unroll
      for (int r = 0; r < 4; ++r)
        Cout[(size_t)(row + r) * N + col] = acc[m][n][r] + bb;
    }
  }
}

extern "C" void kernel_launch(void* const* d_in, const int* in_sizes, int n_in,
                              void* d_out, int out_size, void* d_ws, size_t ws_size,
                              hipStream_t stream) {
  const float* x    = (const float*)d_in[0];
  const float* mask = (const float*)d_in[1];
  const float* wq   = (const float*)d_in[2];
  const float* bq   = (const float*)d_in[3];
  const float* wk   = (const float*)d_in[4];
  const float* bk   = (const float*)d_in[5];
  const float* wv   = (const float*)d_in[6];
  const float* bv   = (const float*)d_in[7];
  const float* wo   = (const float*)d_in[8];
  const float* bo   = (const float*)d_in[9];
  float* out = (float*)d_out;

  const size_t mat = (size_t)NM * ND;
  const size_t wmat = (size_t)ND * ND;
  __hip_bfloat16* xb    = (__hip_bfloat16*)d_ws;
  __hip_bfloat16* WtAll = xb + mat;
  __hip_bfloat16* Qw    = WtAll + 4 * wmat;
  __hip_bfloat16* Kw    = Qw + mat;
  __hip_bfloat16* Vtw   = Kw + mat;
  __hip_bfloat16* Cw    = Vtw + mat;
  float* mpg            = (float*)(Cw + mat);   // 8192 floats
  unsigned* mbits       = (unsigned*)(mpg + NM);  // 4 uints

  // fused prep: convert (3072) + transpose_w (576) + mask (4) = 3652 blocks
  prep_kernel<<<3652, 256, 0, stream>>>(x, mask, wq, wk, wv, wo,
                                        xb, mpg, mbits, WtAll);

  qkv_gemm_kernel<<<dim3(3 * ND / 128, NM / 128), 256, 0, stream>>>(
      xb, WtAll, bq, bk, bv, Qw, Kw, Vtw);

  mha_mfma32_kernel<<<dim3(NS / 128, NH, NB), 256, 0, stream>>>(
      Qw, Kw, Vtw, mpg, mbits, Cw);

  gemm_bt_mfma_kernel<<<dim3(ND / 64, NM / 128), 256, 0, stream>>>(
      Cw, WtAll + 3 * wmat, bo, out, NM, ND, ND);
}